// Round 1
// baseline (1906.877 us; speedup 1.0000x reference)
//
#include <hip/hip_runtime.h>
#include <hip/hip_bf16.h>

#define NN 100000
#define F_IN 128
#define HDIM 64

// ---- degree histogram (counts per dst; self-loop added later as +1) ----
__global__ void k_deg(const int* __restrict__ dst, int E, int* __restrict__ deg) {
    int e = blockIdx.x * blockDim.x + threadIdx.x;
    if (e < E) atomicAdd(&deg[dst[e]], 1);
}

__global__ void k_dinv(const int* __restrict__ deg, float* __restrict__ dinv, int n) {
    int i = blockIdx.x * blockDim.x + threadIdx.x;
    if (i < n) dinv[i] = rsqrtf((float)(deg[i] + 1));  // +1 = self-loop
}

// ---- fp32 GEMM: Y[n][64] = X[n][K] @ W[K][64] ; 4 nodes per 256-thread block ----
template<int K>
__global__ __launch_bounds__(256) void k_gemm(const float* __restrict__ X,
                                              const float* __restrict__ W,
                                              float* __restrict__ Y, int n) {
    __shared__ float Ws[K * 64];
    __shared__ float Xs[4 * K];
    int t = threadIdx.x;
    for (int idx = t; idx < K * 64; idx += 256) Ws[idx] = W[idx];
    int nodeBase = blockIdx.x * 4;
    for (int idx = t; idx < 4 * K; idx += 256) {
        int ln = idx / K, k = idx % K;
        int node = nodeBase + ln;
        Xs[idx] = (node < n) ? X[node * K + k] : 0.f;
    }
    __syncthreads();
    int ln = t >> 6, j = t & 63;
    int node = nodeBase + ln;
    float acc = 0.f;
#pragma unroll 8
    for (int k = 0; k < K; ++k) acc += Xs[ln * K + k] * Ws[k * 64 + j];
    if (node < n) Y[node * 64 + j] = acc;
}

// ---- init accumulator with self-loop term: B[i][j] = H[i][j] * dinv[i]^2 ----
__global__ void k_scale(const float* __restrict__ H, const float* __restrict__ dinv,
                        float* __restrict__ B, int n) {
    int tid = blockIdx.x * 256 + threadIdx.x;
    if (tid < n * 64) {
        int i = tid >> 6;
        float di = dinv[i];
        B[tid] = H[tid] * di * di;
    }
}

// ---- edge scatter: B[d][j] += H[s][j] * dinv[s]*dinv[d]; one wave-quarter... lane j per feature ----
__global__ __launch_bounds__(256) void k_edge(const int* __restrict__ src,
                                              const int* __restrict__ dst,
                                              const float* __restrict__ H,
                                              const float* __restrict__ dinv,
                                              float* __restrict__ B, int E) {
    int tid = blockIdx.x * 256 + threadIdx.x;   // E*64 = 204.8M < 2^31
    int e = tid >> 6;
    int j = tid & 63;
    if (e < E) {
        int s = src[e], d = dst[e];
        float nrm = dinv[s] * dinv[d];
        float v = H[s * 64 + j] * nrm;
        unsafeAtomicAdd(&B[d * 64 + j], v);     // hw global_atomic_add_f32
    }
}

// ---- bias + optional relu ----
__global__ void k_post(const float* __restrict__ B, const float* __restrict__ bias,
                       float* __restrict__ Y, int n, int relu) {
    int tid = blockIdx.x * 256 + threadIdx.x;
    if (tid < n * 64) {
        int j = tid & 63;
        float v = B[tid] + bias[j];
        if (relu) v = fmaxf(v, 0.f);
        Y[tid] = v;
    }
}

// ---- fused: (B2 + b2) @ (Wl1 @ Wl2) + (bl1 @ Wl2 + bl2) -> logits [n][2] ----
__global__ __launch_bounds__(256) void k_final(const float* __restrict__ B2,
                                               const float* __restrict__ b2,
                                               const float* __restrict__ Wl1,
                                               const float* __restrict__ bl1,
                                               const float* __restrict__ Wl2,
                                               const float* __restrict__ bl2,
                                               float* __restrict__ logits, int n) {
    __shared__ float Wc[64][2];
    __shared__ float bc[2];
    __shared__ float b2s[64];
    int t = threadIdx.x;
    if (t < 128) {
        int k = t >> 1, c = t & 1;
        float s = 0.f;
        for (int m = 0; m < 32; ++m) s += Wl1[k * 32 + m] * Wl2[m * 2 + c];
        Wc[k][c] = s;
    } else if (t < 130) {
        int c = t - 128;
        float s = bl2[c];
        for (int m = 0; m < 32; ++m) s += bl1[m] * Wl2[m * 2 + c];
        bc[c] = s;
    } else if (t >= 192) {
        b2s[t - 192] = b2[t - 192];
    }
    __syncthreads();
    int node = blockIdx.x * 256 + t;
    if (node < n) {
        const float* row = B2 + node * 64;
        float a0 = bc[0], a1 = bc[1];
#pragma unroll
        for (int k = 0; k < 64; ++k) {
            float v = row[k] + b2s[k];
            a0 += v * Wc[k][0];
            a1 += v * Wc[k][1];
        }
        logits[node * 2 + 0] = a0;
        logits[node * 2 + 1] = a1;
    }
}

// ---- softmax over axis 0 (per column, 2 columns), single block ----
__global__ __launch_bounds__(1024) void k_softmax(const float* __restrict__ logits,
                                                  float* __restrict__ out, int n) {
    __shared__ float red0[1024], red1[1024];
    int t = threadIdx.x;
    float m0 = -3.4e38f, m1 = -3.4e38f;
    for (int i = t; i < n; i += 1024) {
        m0 = fmaxf(m0, logits[i * 2]);
        m1 = fmaxf(m1, logits[i * 2 + 1]);
    }
    red0[t] = m0; red1[t] = m1;
    __syncthreads();
    for (int s = 512; s > 0; s >>= 1) {
        if (t < s) {
            red0[t] = fmaxf(red0[t], red0[t + s]);
            red1[t] = fmaxf(red1[t], red1[t + s]);
        }
        __syncthreads();
    }
    m0 = red0[0]; m1 = red1[0];
    __syncthreads();
    float s0 = 0.f, s1 = 0.f;
    for (int i = t; i < n; i += 1024) {
        s0 += expf(logits[i * 2] - m0);
        s1 += expf(logits[i * 2 + 1] - m1);
    }
    red0[t] = s0; red1[t] = s1;
    __syncthreads();
    for (int s = 512; s > 0; s >>= 1) {
        if (t < s) {
            red0[t] += red0[t + s];
            red1[t] += red1[t + s];
        }
        __syncthreads();
    }
    float inv0 = 1.f / red0[0], inv1 = 1.f / red1[0];
    for (int i = t; i < n; i += 1024) {
        out[i * 2]     = expf(logits[i * 2] - m0) * inv0;
        out[i * 2 + 1] = expf(logits[i * 2 + 1] - m1) * inv1;
    }
}

extern "C" void kernel_launch(void* const* d_in, const int* in_sizes, int n_in,
                              void* d_out, int out_size, void* d_ws, size_t ws_size,
                              hipStream_t stream) {
    const float* x   = (const float*)d_in[0];
    const int*   ei  = (const int*)d_in[1];
    const float* W1  = (const float*)d_in[2];
    const float* b1  = (const float*)d_in[3];
    const float* W2  = (const float*)d_in[4];
    const float* b2  = (const float*)d_in[5];
    const float* Wl1 = (const float*)d_in[6];
    const float* bl1 = (const float*)d_in[7];
    const float* Wl2 = (const float*)d_in[8];
    const float* bl2 = (const float*)d_in[9];
    float* out = (float*)d_out;

    int N = in_sizes[0] / F_IN;   // 100000
    int E = in_sizes[1] / 2;      // 3200000
    const int* esrc = ei;
    const int* edst = ei + E;

    char* ws = (char*)d_ws;
    int*   deg    = (int*)ws;                         // 400 KB
    float* dinv   = (float*)(ws + 401408);            // 400 KB
    float* bufA   = (float*)(ws + 806912);            // 25.6 MB
    float* bufB   = (float*)(ws + 32407552);          // 25.6 MB
    float* logits = (float*)(ws + 58011648);          // 800 KB

    hipMemsetAsync(deg, 0, N * sizeof(int), stream);

    int eb = (E + 255) / 256;
    int nb = (N + 255) / 256;
    int fb = (N * 64 + 255) / 256;
    int gb = (N + 3) / 4;
    int ebig = (int)(((long long)E * 64 + 255) / 256);

    k_deg<<<eb, 256, 0, stream>>>(edst, E, deg);
    k_dinv<<<nb, 256, 0, stream>>>(deg, dinv, N);

    // layer 1
    k_gemm<128><<<gb, 256, 0, stream>>>(x, W1, bufA, N);
    k_scale<<<fb, 256, 0, stream>>>(bufA, dinv, bufB, N);
    k_edge<<<ebig, 256, 0, stream>>>(esrc, edst, bufA, dinv, bufB, E);
    k_post<<<fb, 256, 0, stream>>>(bufB, b1, bufA, N, 1);

    // layer 2
    k_gemm<64><<<gb, 256, 0, stream>>>(bufA, W2, bufB, N);
    k_scale<<<fb, 256, 0, stream>>>(bufB, dinv, bufA, N);
    k_edge<<<ebig, 256, 0, stream>>>(esrc, edst, bufB, dinv, bufA, E);

    // fused linears + softmax
    k_final<<<nb, 256, 0, stream>>>(bufA, b2, Wl1, bl1, Wl2, bl2, logits, N);
    k_softmax<<<1, 1024, 0, stream>>>(logits, out, N);
}

// Round 2
// 1262.950 us; speedup vs baseline: 1.5099x; 1.5099x over previous
//
#include <hip/hip_runtime.h>
#include <hip/hip_bf16.h>

#define F_IN 128

// ---- degree histogram over dst (self-loop handled as +1 later) ----
__global__ void k_deg(const int* __restrict__ dst, int E, int* __restrict__ deg) {
    int e = blockIdx.x * blockDim.x + threadIdx.x;
    if (e < E) atomicAdd(&deg[dst[e]], 1);
}

// ---- single-block exclusive scan of deg -> offs/cursor; also dinv = rsqrt(deg+1) ----
__global__ __launch_bounds__(1024) void k_scan(const int* __restrict__ deg,
                                               int* __restrict__ offs,
                                               int* __restrict__ cursor,
                                               float* __restrict__ dinv, int n) {
    __shared__ int part[1024];
    int t = threadIdx.x;
    int chunk = (n + 1023) / 1024;
    int beg = t * chunk, end = min(beg + chunk, n);
    int s = 0;
    for (int i = beg; i < end; ++i) s += deg[i];
    part[t] = s;
    __syncthreads();
    for (int d = 1; d < 1024; d <<= 1) {       // Hillis-Steele inclusive scan
        int v = (t >= d) ? part[t - d] : 0;
        __syncthreads();
        part[t] += v;
        __syncthreads();
    }
    int run = (t == 0) ? 0 : part[t - 1];
    for (int i = beg; i < end; ++i) {
        offs[i] = run;
        cursor[i] = run;
        dinv[i] = rsqrtf((float)(deg[i] + 1));
        run += deg[i];
    }
    if (t == 1023) offs[n] = run;              // == E
}

// ---- counting-sort scatter: csr_src grouped by dst ----
__global__ void k_scatter(const int* __restrict__ src, const int* __restrict__ dst,
                          int* __restrict__ cursor, int* __restrict__ csr, int E) {
    int e = blockIdx.x * blockDim.x + threadIdx.x;
    if (e < E) {
        int pos = atomicAdd(&cursor[dst[e]], 1);
        csr[pos] = src[e];
    }
}

// ---- fp32 GEMM: Y[n][64] = (X[n][K] @ W[K][64]) * dinv[n]  (pre-scale fused) ----
template<int K>
__global__ __launch_bounds__(256) void k_gemm(const float* __restrict__ X,
                                              const float* __restrict__ W,
                                              const float* __restrict__ dinv,
                                              float* __restrict__ Y, int n) {
    __shared__ float Ws[K * 64];
    __shared__ float Xs[4 * K];
    int t = threadIdx.x;
    for (int idx = t; idx < K * 64; idx += 256) Ws[idx] = W[idx];
    int nodeBase = blockIdx.x * 4;
    for (int idx = t; idx < 4 * K; idx += 256) {
        int ln = idx / K, k = idx % K;
        int node = nodeBase + ln;
        Xs[idx] = (node < n) ? X[node * K + k] : 0.f;
    }
    __syncthreads();
    int ln = t >> 6, j = t & 63;
    int node = nodeBase + ln;
    float acc = 0.f;
#pragma unroll 8
    for (int k = 0; k < K; ++k) acc += Xs[ln * K + k] * Ws[k * 64 + j];
    if (node < n) Y[node * 64 + j] = acc * dinv[node];
}

// ---- pull-gather: out[d][j] = relu?( dinv[d]*(G[d][j] + sum G[src][j]) + bias[j] ) ----
// one wave per destination node; lane j = feature j
__global__ __launch_bounds__(256) void k_gather(const int* __restrict__ csr,
                                                const int* __restrict__ offs,
                                                const float* __restrict__ G,
                                                const float* __restrict__ dinv,
                                                const float* __restrict__ bias,
                                                float* __restrict__ out, int n, int relu) {
    int w = (blockIdx.x * 256 + threadIdx.x) >> 6;
    int j = threadIdx.x & 63;
    if (w >= n) return;
    int beg = offs[w], end = offs[w + 1];
    float acc = G[w * 64 + j];                 // self-loop term
    int e = beg;
    for (; e + 4 <= end; e += 4) {
        int s0 = csr[e], s1 = csr[e + 1], s2 = csr[e + 2], s3 = csr[e + 3];
        float v0 = G[s0 * 64 + j];
        float v1 = G[s1 * 64 + j];
        float v2 = G[s2 * 64 + j];
        float v3 = G[s3 * 64 + j];
        acc += v0 + v1 + v2 + v3;
    }
    for (; e < end; ++e) acc += G[csr[e] * 64 + j];
    float v = acc * dinv[w] + bias[j];
    if (relu) v = fmaxf(v, 0.f);
    out[w * 64 + j] = v;
}

// ---- fused: B2 @ (Wl1 @ Wl2) + (bl1 @ Wl2 + bl2) -> logits [n][2]  (b2 already in B2) ----
__global__ __launch_bounds__(256) void k_final(const float* __restrict__ B2,
                                               const float* __restrict__ Wl1,
                                               const float* __restrict__ bl1,
                                               const float* __restrict__ Wl2,
                                               const float* __restrict__ bl2,
                                               float* __restrict__ logits, int n) {
    __shared__ float Wc[64][2];
    __shared__ float bc[2];
    int t = threadIdx.x;
    if (t < 128) {
        int k = t >> 1, c = t & 1;
        float s = 0.f;
        for (int m = 0; m < 32; ++m) s += Wl1[k * 32 + m] * Wl2[m * 2 + c];
        Wc[k][c] = s;
    } else if (t < 130) {
        int c = t - 128;
        float s = bl2[c];
        for (int m = 0; m < 32; ++m) s += bl1[m] * Wl2[m * 2 + c];
        bc[c] = s;
    }
    __syncthreads();
    int node = blockIdx.x * 256 + t;
    if (node < n) {
        const float* row = B2 + node * 64;
        float a0 = bc[0], a1 = bc[1];
#pragma unroll
        for (int k = 0; k < 64; ++k) {
            float v = row[k];
            a0 += v * Wc[k][0];
            a1 += v * Wc[k][1];
        }
        logits[node * 2 + 0] = a0;
        logits[node * 2 + 1] = a1;
    }
}

// ---- softmax over axis 0 (per column, 2 columns), single block ----
__global__ __launch_bounds__(1024) void k_softmax(const float* __restrict__ logits,
                                                  float* __restrict__ out, int n) {
    __shared__ float red0[1024], red1[1024];
    int t = threadIdx.x;
    float m0 = -3.4e38f, m1 = -3.4e38f;
    for (int i = t; i < n; i += 1024) {
        m0 = fmaxf(m0, logits[i * 2]);
        m1 = fmaxf(m1, logits[i * 2 + 1]);
    }
    red0[t] = m0; red1[t] = m1;
    __syncthreads();
    for (int s = 512; s > 0; s >>= 1) {
        if (t < s) {
            red0[t] = fmaxf(red0[t], red0[t + s]);
            red1[t] = fmaxf(red1[t], red1[t + s]);
        }
        __syncthreads();
    }
    m0 = red0[0]; m1 = red1[0];
    __syncthreads();
    float s0 = 0.f, s1 = 0.f;
    for (int i = t; i < n; i += 1024) {
        s0 += expf(logits[i * 2] - m0);
        s1 += expf(logits[i * 2 + 1] - m1);
    }
    red0[t] = s0; red1[t] = s1;
    __syncthreads();
    for (int s = 512; s > 0; s >>= 1) {
        if (t < s) {
            red0[t] += red0[t + s];
            red1[t] += red1[t + s];
        }
        __syncthreads();
    }
    float inv0 = 1.f / red0[0], inv1 = 1.f / red1[0];
    for (int i = t; i < n; i += 1024) {
        out[i * 2]     = expf(logits[i * 2] - m0) * inv0;
        out[i * 2 + 1] = expf(logits[i * 2 + 1] - m1) * inv1;
    }
}

extern "C" void kernel_launch(void* const* d_in, const int* in_sizes, int n_in,
                              void* d_out, int out_size, void* d_ws, size_t ws_size,
                              hipStream_t stream) {
    const float* x   = (const float*)d_in[0];
    const int*   ei  = (const int*)d_in[1];
    const float* W1  = (const float*)d_in[2];
    const float* b1  = (const float*)d_in[3];
    const float* W2  = (const float*)d_in[4];
    const float* b2  = (const float*)d_in[5];
    const float* Wl1 = (const float*)d_in[6];
    const float* bl1 = (const float*)d_in[7];
    const float* Wl2 = (const float*)d_in[8];
    const float* bl2 = (const float*)d_in[9];
    float* out = (float*)d_out;

    int N = in_sizes[0] / F_IN;   // 100000
    int E = in_sizes[1] / 2;      // 3200000
    const int* esrc = ei;
    const int* edst = ei + E;

    char* ws = (char*)d_ws;
    size_t off = 0;
    auto alloc = [&](size_t bytes) { void* p = ws + off; off += (bytes + 255) & ~(size_t)255; return p; };
    int*   deg    = (int*)alloc((size_t)N * 4);
    int*   offs   = (int*)alloc((size_t)(N + 1) * 4);
    int*   cursor = (int*)alloc((size_t)N * 4);
    float* dinv   = (float*)alloc((size_t)N * 4);
    int*   csr    = (int*)alloc((size_t)E * 4);        // 12.8 MB
    float* bufA   = (float*)alloc((size_t)N * 64 * 4); // 25.6 MB
    float* bufB   = (float*)alloc((size_t)N * 64 * 4); // 25.6 MB
    float* logits = (float*)alloc((size_t)N * 2 * 4);

    hipMemsetAsync(deg, 0, N * sizeof(int), stream);

    int eb = (E + 255) / 256;
    int nb = (N + 255) / 256;
    int gb = (N + 3) / 4;
    int wb = (N * 64 + 255) / 256;   // one wave per node → N*64 threads

    // CSR build (shared by both layers)
    k_deg<<<eb, 256, 0, stream>>>(edst, E, deg);
    k_scan<<<1, 1024, 0, stream>>>(deg, offs, cursor, dinv, N);
    k_scatter<<<eb, 256, 0, stream>>>(esrc, edst, cursor, csr, E);

    // layer 1: G1 = (x@W1)*dinv ; H1 = relu(dinv*(G1[d]+sum G1[src]) + b1)
    k_gemm<128><<<gb, 256, 0, stream>>>(x, W1, dinv, bufA, N);
    k_gather<<<wb, 256, 0, stream>>>(csr, offs, bufA, dinv, b1, bufB, N, 1);

    // layer 2: G2 = (H1@W2)*dinv ; B2 = dinv*(G2[d]+sum G2[src]) + b2
    k_gemm<64><<<gb, 256, 0, stream>>>(bufB, W2, dinv, bufA, N);
    k_gather<<<wb, 256, 0, stream>>>(csr, offs, bufA, dinv, b2, bufB, N, 0);

    // fused linears + softmax
    k_final<<<nb, 256, 0, stream>>>(bufB, Wl1, bl1, Wl2, bl2, logits, N);
    k_softmax<<<1, 1024, 0, stream>>>(logits, out, N);
}

// Round 3
// 1018.385 us; speedup vs baseline: 1.8725x; 1.2401x over previous
//
#include <hip/hip_runtime.h>
#include <hip/hip_bf16.h>

#define F_IN 128

// ---- degree histogram over dst (self-loop handled as +1 later) ----
__global__ void k_deg(const int* __restrict__ dst, int E, int* __restrict__ deg) {
    int e = blockIdx.x * blockDim.x + threadIdx.x;
    if (e < E) atomicAdd(&deg[dst[e]], 1);
}

// ---- parallel scan, stage 1: per-block reduce of deg ----
__global__ __launch_bounds__(256) void k_blockred(const int* __restrict__ deg,
                                                  int* __restrict__ bsum, int n) {
    __shared__ int red[256];
    int t = threadIdx.x;
    int i = blockIdx.x * 256 + t;
    red[t] = (i < n) ? deg[i] : 0;
    __syncthreads();
    for (int s = 128; s > 0; s >>= 1) {
        if (t < s) red[t] += red[t + s];
        __syncthreads();
    }
    if (t == 0) bsum[blockIdx.x] = red[0];
}

// ---- stage 2: single small block, exclusive scan of block sums (nb <= 1024) ----
__global__ __launch_bounds__(1024) void k_bscan(int* __restrict__ bsum, int nb) {
    __shared__ int part[1024];
    int t = threadIdx.x;
    int v = (t < nb) ? bsum[t] : 0;
    part[t] = v;
    __syncthreads();
    for (int d = 1; d < 1024; d <<= 1) {
        int u = (t >= d) ? part[t - d] : 0;
        __syncthreads();
        part[t] += u;
        __syncthreads();
    }
    if (t < nb) bsum[t] = part[t] - v;   // exclusive
}

// ---- stage 3: per-block scan + block offset; write offs/cursor/dinv ----
__global__ __launch_bounds__(256) void k_scan3(const int* __restrict__ deg,
                                               const int* __restrict__ bsum,
                                               int* __restrict__ offs,
                                               int* __restrict__ cursor,
                                               float* __restrict__ dinv, int n) {
    __shared__ int red[256];
    int t = threadIdx.x;
    int i = blockIdx.x * 256 + t;
    int v = (i < n) ? deg[i] : 0;
    red[t] = v;
    __syncthreads();
    for (int d = 1; d < 256; d <<= 1) {
        int u = (t >= d) ? red[t - d] : 0;
        __syncthreads();
        red[t] += u;
        __syncthreads();
    }
    int excl = red[t] - v + bsum[blockIdx.x];
    if (i < n) {
        offs[i] = excl;
        cursor[i] = excl;
        dinv[i] = rsqrtf((float)(v + 1));
        if (i == n - 1) offs[n] = excl + v;
    }
}

// ---- counting-sort scatter: csr_src grouped by dst ----
__global__ void k_scatter(const int* __restrict__ src, const int* __restrict__ dst,
                          int* __restrict__ cursor, int* __restrict__ csr, int E) {
    int e = blockIdx.x * blockDim.x + threadIdx.x;
    if (e < E) {
        int pos = atomicAdd(&cursor[dst[e]], 1);
        csr[pos] = src[e];
    }
}

// ---- fp32 GEMM: Y[n][64] = (X[n][K] @ W[K][64]) * dinv[n]  (pre-scale fused) ----
template<int K>
__global__ __launch_bounds__(256) void k_gemm(const float* __restrict__ X,
                                              const float* __restrict__ W,
                                              const float* __restrict__ dinv,
                                              float* __restrict__ Y, int n) {
    __shared__ float Ws[K * 64];
    __shared__ float Xs[4 * K];
    int t = threadIdx.x;
    for (int idx = t; idx < K * 64; idx += 256) Ws[idx] = W[idx];
    int nodeBase = blockIdx.x * 4;
    for (int idx = t; idx < 4 * K; idx += 256) {
        int ln = idx / K, k = idx % K;
        int node = nodeBase + ln;
        Xs[idx] = (node < n) ? X[node * K + k] : 0.f;
    }
    __syncthreads();
    int ln = t >> 6, j = t & 63;
    int node = nodeBase + ln;
    float acc = 0.f;
#pragma unroll 8
    for (int k = 0; k < K; ++k) acc += Xs[ln * K + k] * Ws[k * 64 + j];
    if (node < n) Y[node * 64 + j] = acc * dinv[node];
}

// ---- pull-gather: out[d][j] = relu?( dinv[d]*(G[d][j] + sum G[src][j]) + bias[j] ) ----
__global__ __launch_bounds__(256) void k_gather(const int* __restrict__ csr,
                                                const int* __restrict__ offs,
                                                const float* __restrict__ G,
                                                const float* __restrict__ dinv,
                                                const float* __restrict__ bias,
                                                float* __restrict__ out, int n, int relu) {
    int w = (blockIdx.x * 256 + threadIdx.x) >> 6;
    int j = threadIdx.x & 63;
    if (w >= n) return;
    int beg = offs[w], end = offs[w + 1];
    float acc = G[w * 64 + j];                 // self-loop term
    int e = beg;
    for (; e + 4 <= end; e += 4) {
        int s0 = csr[e], s1 = csr[e + 1], s2 = csr[e + 2], s3 = csr[e + 3];
        float v0 = G[s0 * 64 + j];
        float v1 = G[s1 * 64 + j];
        float v2 = G[s2 * 64 + j];
        float v3 = G[s3 * 64 + j];
        acc += v0 + v1 + v2 + v3;
    }
    for (; e < end; ++e) acc += G[csr[e] * 64 + j];
    float v = acc * dinv[w] + bias[j];
    if (relu) v = fmaxf(v, 0.f);
    out[w * 64 + j] = v;
}

// ---- fused: B2 @ (Wl1 @ Wl2) + (bl1 @ Wl2 + bl2) -> logits [n][2] ----
__global__ __launch_bounds__(256) void k_final(const float* __restrict__ B2,
                                               const float* __restrict__ Wl1,
                                               const float* __restrict__ bl1,
                                               const float* __restrict__ Wl2,
                                               const float* __restrict__ bl2,
                                               float* __restrict__ logits, int n) {
    __shared__ float Wc[64][2];
    __shared__ float bc[2];
    int t = threadIdx.x;
    if (t < 128) {
        int k = t >> 1, c = t & 1;
        float s = 0.f;
        for (int m = 0; m < 32; ++m) s += Wl1[k * 32 + m] * Wl2[m * 2 + c];
        Wc[k][c] = s;
    } else if (t < 130) {
        int c = t - 128;
        float s = bl2[c];
        for (int m = 0; m < 32; ++m) s += bl1[m] * Wl2[m * 2 + c];
        bc[c] = s;
    }
    __syncthreads();
    int node = blockIdx.x * 256 + t;
    if (node < n) {
        const float* row = B2 + node * 64;
        float a0 = bc[0], a1 = bc[1];
#pragma unroll
        for (int k = 0; k < 64; ++k) {
            float v = row[k];
            a0 += v * Wc[k][0];
            a1 += v * Wc[k][1];
        }
        logits[node * 2 + 0] = a0;
        logits[node * 2 + 1] = a1;
    }
}

// ---- softmax over axis 0 (per column, 2 columns), single block ----
__global__ __launch_bounds__(1024) void k_softmax(const float* __restrict__ logits,
                                                  float* __restrict__ out, int n) {
    __shared__ float red0[1024], red1[1024];
    int t = threadIdx.x;
    float m0 = -3.4e38f, m1 = -3.4e38f;
    for (int i = t; i < n; i += 1024) {
        m0 = fmaxf(m0, logits[i * 2]);
        m1 = fmaxf(m1, logits[i * 2 + 1]);
    }
    red0[t] = m0; red1[t] = m1;
    __syncthreads();
    for (int s = 512; s > 0; s >>= 1) {
        if (t < s) {
            red0[t] = fmaxf(red0[t], red0[t + s]);
            red1[t] = fmaxf(red1[t], red1[t + s]);
        }
        __syncthreads();
    }
    m0 = red0[0]; m1 = red1[0];
    __syncthreads();
    float s0 = 0.f, s1 = 0.f;
    for (int i = t; i < n; i += 1024) {
        s0 += expf(logits[i * 2] - m0);
        s1 += expf(logits[i * 2 + 1] - m1);
    }
    red0[t] = s0; red1[t] = s1;
    __syncthreads();
    for (int s = 512; s > 0; s >>= 1) {
        if (t < s) {
            red0[t] += red0[t + s];
            red1[t] += red1[t + s];
        }
        __syncthreads();
    }
    float inv0 = 1.f / red0[0], inv1 = 1.f / red1[0];
    for (int i = t; i < n; i += 1024) {
        out[i * 2]     = expf(logits[i * 2] - m0) * inv0;
        out[i * 2 + 1] = expf(logits[i * 2 + 1] - m1) * inv1;
    }
}

extern "C" void kernel_launch(void* const* d_in, const int* in_sizes, int n_in,
                              void* d_out, int out_size, void* d_ws, size_t ws_size,
                              hipStream_t stream) {
    const float* x   = (const float*)d_in[0];
    const int*   ei  = (const int*)d_in[1];
    const float* W1  = (const float*)d_in[2];
    const float* b1  = (const float*)d_in[3];
    const float* W2  = (const float*)d_in[4];
    const float* b2  = (const float*)d_in[5];
    const float* Wl1 = (const float*)d_in[6];
    const float* bl1 = (const float*)d_in[7];
    const float* Wl2 = (const float*)d_in[8];
    const float* bl2 = (const float*)d_in[9];
    float* out = (float*)d_out;

    int N = in_sizes[0] / F_IN;   // 100000
    int E = in_sizes[1] / 2;      // 3200000
    const int* esrc = ei;
    const int* edst = ei + E;

    char* ws = (char*)d_ws;
    size_t off = 0;
    auto alloc = [&](size_t bytes) { void* p = ws + off; off += (bytes + 255) & ~(size_t)255; return p; };
    int*   deg    = (int*)alloc((size_t)N * 4);
    int*   offs   = (int*)alloc((size_t)(N + 1) * 4);
    int*   cursor = (int*)alloc((size_t)N * 4);
    float* dinv   = (float*)alloc((size_t)N * 4);
    int*   bsum   = (int*)alloc((size_t)1024 * 4);
    int*   csr    = (int*)alloc((size_t)E * 4);        // 12.8 MB
    float* bufA   = (float*)alloc((size_t)N * 64 * 4); // 25.6 MB
    float* bufB   = (float*)alloc((size_t)N * 64 * 4); // 25.6 MB
    float* logits = (float*)alloc((size_t)N * 2 * 4);

    hipMemsetAsync(deg, 0, N * sizeof(int), stream);

    int eb = (E + 255) / 256;
    int nb = (N + 255) / 256;   // 391 — also the scan block count (<=1024)
    int gb = (N + 3) / 4;
    int wb = (N * 64 + 255) / 256;

    // CSR build (shared by both layers)
    k_deg<<<eb, 256, 0, stream>>>(edst, E, deg);
    k_blockred<<<nb, 256, 0, stream>>>(deg, bsum, N);
    k_bscan<<<1, 1024, 0, stream>>>(bsum, nb);
    k_scan3<<<nb, 256, 0, stream>>>(deg, bsum, offs, cursor, dinv, N);
    k_scatter<<<eb, 256, 0, stream>>>(esrc, edst, cursor, csr, E);

    // layer 1: G1 = (x@W1)*dinv ; H1 = relu(dinv*(G1[d]+sum G1[src]) + b1)
    k_gemm<128><<<gb, 256, 0, stream>>>(x, W1, dinv, bufA, N);
    k_gather<<<wb, 256, 0, stream>>>(csr, offs, bufA, dinv, b1, bufB, N, 1);

    // layer 2: G2 = (H1@W2)*dinv ; B2 = dinv*(G2[d]+sum G2[src]) + b2
    k_gemm<64><<<gb, 256, 0, stream>>>(bufB, W2, dinv, bufA, N);
    k_gather<<<wb, 256, 0, stream>>>(csr, offs, bufA, dinv, b2, bufB, N, 0);

    // fused linears + softmax
    k_final<<<nb, 256, 0, stream>>>(bufB, Wl1, bl1, Wl2, bl2, logits, N);
    k_softmax<<<1, 1024, 0, stream>>>(logits, out, N);
}